// Round 9
// baseline (57.223 us; speedup 1.0000x reference)
//
#include <hip/hip_runtime.h>

// RPNPooling: B=2, H=128, W=128, C=256, N=512, POOL=14
// out[q,i,j,ch], q in [0,1024), i,j in [0,14), ch in [0,256)
// Reference quirk: r-axis (feature H index) derives from roi x-coords,
// c-axis (feature W index) derives from roi y-coords. Replicated verbatim.
//
// R8 = R5 register-rolling waves
//    + R7 streaming stores (sc0 sc1 nt: bypass L2 allocation)
//    + R3 Morton ROI schedule (finer 4-bit keys): each XCD gets 128
//      spatially-clustered ROIs whose patches fit its (now write-clean)
//      4 MiB L2, eliminating the ~110 MB HBM feature re-fetch.

typedef float f32x4 __attribute__((ext_vector_type(4)));

#define NROI 1024
#define WAVES_TOTAL (NROI * 14)      // 14336
#define THREADS 256                  // 4 waves/block
#define NBLK (WAVES_TOTAL / 4)       // 3584, % 8 == 0

__device__ __forceinline__ unsigned spread4(unsigned v) {
    v &= 15u;
    return (v & 1u) | ((v & 2u) << 1) | ((v & 4u) << 2) | ((v & 8u) << 3);
}

// One block, 1024 threads: sort ROI indices by (batch, Morton(x1>>3, y1>>3)).
// Keys unique (low 10 bits = q) => deterministic permutation.
__global__ __launch_bounds__(1024) void roi_sort_kernel(
    const int* __restrict__ roi, int* __restrict__ perm)
{
    __shared__ unsigned key[NROI];
    const int t = threadIdx.x;
    const int4 rr = ((const int4*)roi)[t];
    const int b = t >> 9;
    // r-axis start = x1 = rr.y; c-axis start = y1 = rr.x (reference swap)
    const unsigned m = spread4((unsigned)rr.y >> 3) | (spread4((unsigned)rr.x >> 3) << 1);
    key[t] = ((((unsigned)b << 8) | m) << 10) | (unsigned)t;
    __syncthreads();
    for (int size = 2; size <= NROI; size <<= 1) {
        for (int stride = size >> 1; stride > 0; stride >>= 1) {
            const int p = t ^ stride;
            const unsigned a  = key[t];
            const unsigned bk = key[p];
            __syncthreads();
            const bool asc = ((t & size) == 0);
            const bool keepmin = ((t < p) == asc);
            key[t] = keepmin ? min(a, bk) : max(a, bk);
            __syncthreads();
        }
    }
    perm[t] = (int)(key[t] & 1023u);
}

__global__ __launch_bounds__(THREADS) void rpn_pool_kernel(
    const float* __restrict__ feat,   // [2,128,128,256]
    const int*   __restrict__ roi,    // [1024,4] = y1,x1,y2,x2
    const int*   __restrict__ perm,   // [1024] spatial schedule
    float*       __restrict__ out)    // [1024,14,14,256]
{
    const int lane = threadIdx.x & 63;
    const int wv   = threadIdx.x >> 6;

    // XCD chunking (bijective): XCD k owns schedule slots [k*128,(k+1)*128)
    // — consecutive in Morton order => spatially clustered patches in its L2.
    const int d   = blockIdx.x;
    const int blk = (d & 7) * (NBLK / 8) + (d >> 3);
    const int W   = blk * 4 + wv;     // wave id in [0, 14336)
    const int g   = W / 14;           // schedule slot
    const int j   = W - g * 14;
    const int q   = perm[g];          // actual ROI index
    const int b   = q >> 9;

    const int4 rr = ((const int4*)roi)[q];
    const int y1 = rr.x, x1 = rr.y, y2 = rr.z, x2 = rr.w;
    const int sR = x2 - x1;           // H-extent from x coords (reference swap)
    const int sC = y2 - y1;           // W-extent from y coords

    // Column constants for this wave
    const int pc  = j * sC;
    const int ic0 = pc / 14;
    const float fc  = (float)(pc - ic0 * 14) * (1.0f / 14.0f);
    const float wc1 = 1.0f - fc;
    const int c0 = ic0;
    const int c1 = min(ic0 + 1, sC - 1);

    const size_t SB4 = (size_t)128 * 128 * 64;   // f32x4 strides
    const size_t SR4 = (size_t)128 * 64;
    const f32x4* base = (const f32x4*)feat + (size_t)b * SB4
                        + (size_t)x1 * SR4 + (size_t)y1 * 64 + lane;
    const size_t o0 = (size_t)c0 * 64, o1 = (size_t)c1 * 64;

    // Prologue: rows 0 and rB=min(1,sR-1)  (sR >= 8 so rB = 1)
    int rA = 0, rB = min(1, sR - 1);
    f32x4 a0 = base[o0];
    f32x4 a1 = base[o1];
    f32x4 b0 = base[(size_t)rB * SR4 + o0];
    f32x4 b1 = base[(size_t)rB * SR4 + o1];

    f32x4* outp = (f32x4*)out + ((size_t)q * 196 + j) * 64 + lane;

    for (int i = 0; i < 14; ++i) {
        const int pr = i * sR;                    // rA == pr/14 (invariant)
        const float fr = (float)(pr - rA * 14) * (1.0f / 14.0f);

        // Prefetch next step's new row (wave-uniform branch).
        int nA = rA, nB = rB;
        f32x4 p0, p1;
        bool adv = false;
        if (i < 13) {
            nA = ((i + 1) * sR) / 14;
            nB = min(nA + 1, sR - 1);
            if (nB > rB) {
                p0 = base[(size_t)nB * SR4 + o0];
                p1 = base[(size_t)nB * SR4 + o1];
                adv = true;
            }
        }

        f32x4 o = (a0 * wc1 + a1 * fc) * (1.0f - fr) + (b0 * wc1 + b1 * fc) * fr;

        // Streaming store: bypass L2 allocation, non-temporal at L3.
        f32x4* p = outp + (size_t)i * 14 * 64;
        asm volatile("global_store_dwordx4 %0, %1, off sc0 sc1 nt"
                     :: "v"(p), "v"(o) : "memory");

        if (nA > rA) { a0 = b0; a1 = b1; }        // adv => nA > rA; coherent
        if (adv)     { b0 = p0; b1 = p1; }
        rA = nA; rB = nB;
    }
}

extern "C" void kernel_launch(void* const* d_in, const int* in_sizes, int n_in,
                              void* d_out, int out_size, void* d_ws, size_t ws_size,
                              hipStream_t stream) {
    const float* feat = (const float*)d_in[0];
    const int*   roi  = (const int*)d_in[1];
    float* out = (float*)d_out;
    int*   perm = (int*)d_ws;

    roi_sort_kernel<<<1, 1024, 0, stream>>>(roi, perm);
    rpn_pool_kernel<<<NBLK, THREADS, 0, stream>>>(feat, roi, perm, out);
}

// Round 10
// 50.438 us; speedup vs baseline: 1.1345x; 1.1345x over previous
//
#include <hip/hip_runtime.h>

// RPNPooling: B=2, H=128, W=128, C=256, N=512, POOL=14
// out[q,i,j,ch], q in [0,1024), i,j in [0,14), ch in [0,256)
// Reference quirk: r-axis (feature H index) derives from roi x-coords,
// c-axis (feature W index) derives from roi y-coords. Replicated verbatim.
//
// R9: wave-per-(q,i) OUTPUT ROW (R5 was wave-per-(q,j) column). Columns
// advance monotonically by <=1 per j-step (slope sC/14 <= 15/14; at sC=15
// the floor increments are exactly 1), so the same register-rolling +
// one-step-ahead prefetch works with rows fixed and columns rolling.
// Payoff: each wave's 14 stores are CONTIGUOUS (14 KB), each block writes
// 56 KB contiguous, each XCD one contiguous ~25 MB slab -> DRAM page/burst
// locality of the dominant 205.5 MB write stream matches the fill kernel.

typedef float f32x4 __attribute__((ext_vector_type(4)));

#define NROI 1024
#define WAVES_TOTAL (NROI * 14)      // 14336
#define THREADS 256                  // 4 waves/block
#define NBLK (WAVES_TOTAL / 4)       // 3584, % 8 == 0

__global__ __launch_bounds__(THREADS) void rpn_pool_kernel(
    const float* __restrict__ feat,   // [2,128,128,256]
    const int*   __restrict__ roi,    // [1024,4] = y1,x1,y2,x2
    float*       __restrict__ out)    // [1024,14,14,256]
{
    const int lane = threadIdx.x & 63;
    const int wv   = threadIdx.x >> 6;

    // XCD chunking (bijective, 3584 % 8 == 0): XCD k owns q in [k*128,(k+1)*128)
    // -> one contiguous ~25 MB output slab per XCD.
    const int d   = blockIdx.x;
    const int blk = (d & 7) * (NBLK / 8) + (d >> 3);
    const int W   = blk * 4 + wv;     // wave id in [0, 14336)
    const int q   = W / 14;
    const int i   = W - q * 14;       // this wave's output row
    const int b   = q >> 9;

    const int4 rr = ((const int4*)roi)[q];
    const int y1 = rr.x, x1 = rr.y, y2 = rr.z, x2 = rr.w;
    const int sR = x2 - x1;           // H-extent from x coords (reference swap)
    const int sC = y2 - y1;           // W-extent from y coords

    // Row constants for this wave (fixed rows r0, r1)
    const int pr  = i * sR;
    const int ir0 = pr / 14;
    const float fr  = (float)(pr - ir0 * 14) * (1.0f / 14.0f);
    const float wr1 = 1.0f - fr;
    const int r0 = ir0;
    const int r1 = min(ir0 + 1, sR - 1);

    const size_t SB4 = (size_t)128 * 128 * 64;   // f32x4 strides
    const size_t SR4 = (size_t)128 * 64;
    const f32x4* base = (const f32x4*)feat + (size_t)b * SB4
                        + (size_t)x1 * SR4 + (size_t)y1 * 64 + lane;
    const f32x4* rowA = base + (size_t)r0 * SR4;   // row r0, column-indexed
    const f32x4* rowB = base + (size_t)r1 * SR4;

    // Prologue: columns 0 and cB=min(1,sC-1)=1 (sC >= 8)
    int cA = 0, cB = min(1, sC - 1);
    f32x4 a0 = rowA[0];
    f32x4 a1 = rowA[(size_t)cB * 64];
    f32x4 b0 = rowB[0];
    f32x4 b1 = rowB[(size_t)cB * 64];

    f32x4* outp = (f32x4*)out + ((size_t)q * 196 + (size_t)i * 14) * 64 + lane;

    for (int j = 0; j < 14; ++j) {
        const int pc = j * sC;                    // cA == pc/14 (invariant)
        const float fc = (float)(pc - cA * 14) * (1.0f / 14.0f);

        // Prefetch next step's new column (wave-uniform branch).
        int nA = cA, nB = cB;
        f32x4 p0, p1;
        bool adv = false;
        if (j < 13) {
            nA = ((j + 1) * sC) / 14;
            nB = min(nA + 1, sC - 1);
            if (nB > cB) {
                p0 = rowA[(size_t)nB * 64];
                p1 = rowB[(size_t)nB * 64];
                adv = true;
            }
        }

        f32x4 o = (a0 * (1.0f - fc) + a1 * fc) * wr1 + (b0 * (1.0f - fc) + b1 * fc) * fr;

        // Streaming store, contiguous across j (1 KB per step per wave).
        f32x4* p = outp + (size_t)j * 64;
        asm volatile("global_store_dwordx4 %0, %1, off sc0 sc1 nt"
                     :: "v"(p), "v"(o) : "memory");

        if (nA > cA) { a0 = a1; b0 = b1; }        // adv => nA > cA; coherent
        if (adv)     { a1 = p0; b1 = p1; }
        cA = nA; cB = nB;
    }
}

extern "C" void kernel_launch(void* const* d_in, const int* in_sizes, int n_in,
                              void* d_out, int out_size, void* d_ws, size_t ws_size,
                              hipStream_t stream) {
    const float* feat = (const float*)d_in[0];
    const int*   roi  = (const int*)d_in[1];
    float* out = (float*)d_out;

    rpn_pool_kernel<<<NBLK, THREADS, 0, stream>>>(feat, roi, out);
}